// Round 5
// baseline (137671.362 us; speedup 1.0000x reference)
//
#include <hip/hip_runtime.h>
#include <hip/hip_fp16.h>

#define B_SZ    64
#define T_STEPS 512
#define U1      128
#define S1      128
#define U2      256
#define S2      128
#define NUNF    6

__device__ __forceinline__ float fast_exp2(float x) { return __builtin_amdgcn_exp2f(x); }
__device__ __forceinline__ float fast_rcp(float x)  { return __builtin_amdgcn_rcpf(x); }

// ---------------------------------------------------------------------------
// Param transform, fp16-packed SoA: AB = half2(sigma*log2e, mu*sigma*log2e),
// W = half(w*erev).  sigmoid((v-mu)*sigma) = 1/(1+exp2(B - A*v)); |W| = w*mask.
// ---------------------------------------------------------------------------
__global__ void prep_half(const float* __restrict__ sg, const float* __restrict__ mu,
                          const float* __restrict__ w, const float* __restrict__ er,
                          __half2* __restrict__ AB, __half* __restrict__ W, int n)
{
    int i = blockIdx.x * 256 + threadIdx.x;
    if (i >= n) return;
    const float L2E = 1.4426950408889634f;
    float a = sg[i] * L2E;
    AB[i] = __floats2half2_rn(a, mu[i] * a);
    W[i]  = __float2half_rn(w[i] * er[i]);
}

__global__ void prep_vec(const float* __restrict__ gleak, const float* __restrict__ vleak,
                         const float* __restrict__ cm,
                         float* __restrict__ cmt, float* __restrict__ nb,
                         float* __restrict__ db, int n)
{
    int i = blockIdx.x * 256 + threadIdx.x;
    if (i >= n) return;
    float c6 = cm[i] * 6.f;
    float gl = gleak[i];
    cmt[i] = c6;
    nb[i]  = gl * vleak[i];
    db[i]  = c6 + gl + 1e-8f;
}

// ---------------------------------------------------------------------------
// Layer 1: S=128, U=128. 512 threads: uo=tid&127, g=tid>>7 (4 groups x 32 s).
// ALL 64 param pairs/thread cached in registers as fp32 (192 VGPRs of params).
// waves_per_eu(2,2): cap = 2 waves/SIMD -> up to 256 VGPRs, no spill.
// ---------------------------------------------------------------------------
__global__ __launch_bounds__(512)
__attribute__((amdgpu_waves_per_eu(2, 2)))
void ltc1(
    const float* __restrict__ x,
    const float* __restrict__ in_w, const float* __restrict__ in_b,
    const __half2* __restrict__ ABs, const __half* __restrict__ Ws,
    const __half2* __restrict__ ABr, const __half* __restrict__ Wr,
    const float* __restrict__ cmt, const float* __restrict__ nbv, const float* __restrict__ dbv,
    const float* __restrict__ ow, const float* __restrict__ ob,
    float* __restrict__ h1)
{
    const int b   = blockIdx.x;
    const int tid = threadIdx.x;
    const int uo  = tid & (U1 - 1);
    const int g   = tid >> 7;               // 0..3, 32 inputs each

    __shared__ float  v1[U1];
    __shared__ float  ibuf[S1];
    __shared__ float2 red[4][U1];
    __shared__ float  nbs[U1], dbs[U1];

    // register-cache all params (fp32, no per-use cvt)
    float sA[32], sB[32], sW[32], rA[32], rB[32], rW[32];
    #pragma unroll
    for (int j = 0; j < 32; ++j) {
        size_t idx = (size_t)(g * 32 + j) * U1 + uo;
        __half2 a1 = ABs[idx]; sA[j] = __low2float(a1); sB[j] = __high2float(a1);
        sW[j] = __half2float(Ws[idx]);
        __half2 a2 = ABr[idx]; rA[j] = __low2float(a2); rB[j] = __high2float(a2);
        rW[j] = __half2float(Wr[idx]);
    }

    float c_cmt = 0, c_nb = 0, c_db = 0, c_iw = 0, c_ib = 0, c_ow = 0, c_ob = 0;
    if (tid < U1) {
        v1[tid] = 0.f;
        c_cmt = cmt[tid]; c_nb = nbv[tid]; c_db = dbv[tid];
        c_iw = in_w[tid]; c_ib = in_b[tid];
        c_ow = ow[tid];   c_ob = ob[tid];
    }
    const float* xb = x  + (size_t)b * T_STEPS * S1;
    float*       hb = h1 + (size_t)b * T_STEPS * U1;

    for (int t = 0; t < T_STEPS; ++t) {
        if (tid < S1) ibuf[tid] = fmaf(xb[t * S1 + tid], c_iw, c_ib);
        __syncthreads();

        {   // sensory partials: 32 cached pairs
            float an = 0.f, ad = 0.f;
            #pragma unroll
            for (int jj = 0; jj < 8; ++jj) {
                float4 iv = *reinterpret_cast<const float4*>(&ibuf[g * 32 + jj * 4]);
                float vals[4] = {iv.x, iv.y, iv.z, iv.w};
                #pragma unroll
                for (int q = 0; q < 4; ++q) {
                    int j = jj * 4 + q;
                    float e = fast_exp2(sB[j] - sA[j] * vals[q]);
                    float r = fast_rcp(1.f + e);
                    an = fmaf(sW[j], r, an);
                    ad = fmaf(fabsf(sW[j]), r, ad);
                }
            }
            red[g][uo] = make_float2(an, ad);
        }
        __syncthreads();
        if (tid < U1) {
            float2 r0 = red[0][tid], r1 = red[1][tid], r2 = red[2][tid], r3 = red[3][tid];
            nbs[tid] = c_nb + ((r0.x + r1.x) + (r2.x + r3.x));
            dbs[tid] = c_db + ((r0.y + r1.y) + (r2.y + r3.y));
        }
        __syncthreads();

        for (int k = 0; k < NUNF; ++k) {
            float an = 0.f, ad = 0.f;
            #pragma unroll
            for (int jj = 0; jj < 8; ++jj) {
                float4 vv = *reinterpret_cast<const float4*>(&v1[g * 32 + jj * 4]);
                float vals[4] = {vv.x, vv.y, vv.z, vv.w};
                #pragma unroll
                for (int q = 0; q < 4; ++q) {
                    int j = jj * 4 + q;
                    float e = fast_exp2(rB[j] - rA[j] * vals[q]);
                    float r = fast_rcp(1.f + e);
                    an = fmaf(rW[j], r, an);
                    ad = fmaf(fabsf(rW[j]), r, ad);
                }
            }
            red[g][uo] = make_float2(an, ad);
            __syncthreads();
            if (tid < U1) {
                float2 r0 = red[0][tid], r1 = red[1][tid], r2 = red[2][tid], r3 = red[3][tid];
                float wn = nbs[tid] + ((r0.x + r1.x) + (r2.x + r3.x));
                float wd = dbs[tid] + ((r0.y + r1.y) + (r2.y + r3.y));
                v1[tid] = fmaf(c_cmt, v1[tid], wn) * fast_rcp(wd);
            }
            __syncthreads();
        }
        if (tid < U1) hb[t * U1 + tid] = fmaf(v1[tid], c_ow, c_ob);
    }
}

// ---------------------------------------------------------------------------
// Layer 2: S=128, U=256. 512 threads: uo=tid&255, g=tid>>8 (2 groups x 128 s).
// ALL 128 recurrent pairs/thread cached as packed fp16 (192 VGPRs of params);
// sensory matrix (1/13 of traffic) streamed from L2.
// ---------------------------------------------------------------------------
__global__ __launch_bounds__(512)
__attribute__((amdgpu_waves_per_eu(2, 2)))
void ltc2(
    const float* __restrict__ h1,
    const float* __restrict__ in_w, const float* __restrict__ in_b,
    const __half2* __restrict__ ABs, const __half* __restrict__ Ws,
    const __half2* __restrict__ ABr, const __half* __restrict__ Wr,
    const float* __restrict__ cmt, const float* __restrict__ nbv, const float* __restrict__ dbv,
    const float* __restrict__ ow, const float* __restrict__ ob,
    float* __restrict__ h2)                      // [64][512][64]
{
    const int b   = blockIdx.x;
    const int tid = threadIdx.x;
    const int uo  = tid & (U2 - 1);
    const int g   = tid >> 8;               // 0..1, 128 recurrent inputs each

    __shared__ float  v2[U2];
    __shared__ float  ibuf[S2];
    __shared__ float2 red[2][U2];
    __shared__ float  nbs[U2], dbs[U2];

    // register-cache recurrent params, fp16-packed: 128 AB dwords + 64 W2 dwords
    __half2 cAB[128];
    __half2 cW[64];
    #pragma unroll
    for (int kk = 0; kk < 64; ++kk) {
        size_t i0 = (size_t)(g * 128 + 2 * kk) * U2 + uo;
        cAB[2 * kk]     = ABr[i0];
        cAB[2 * kk + 1] = ABr[i0 + U2];
        cW[kk] = __halves2half2(Wr[i0], Wr[i0 + U2]);
    }

    float c_cmt = 0, c_nb = 0, c_db = 0;
    if (tid < U2) {
        v2[tid] = 0.f;
        c_cmt = cmt[tid]; c_nb = nbv[tid]; c_db = dbv[tid];
    }
    float c_iw = 0, c_ib = 0;
    if (tid < S2) { c_iw = in_w[tid]; c_ib = in_b[tid]; }
    float c_ow = 0, c_ob = 0;
    if (tid < 64) { c_ow = ow[tid]; c_ob = ob[tid]; }

    const float* hb = h1 + (size_t)b * T_STEPS * S2;
    float*       op = h2 + (size_t)b * T_STEPS * 64;

    const __half2* pABs = ABs + (size_t)(g * 64) * U2 + uo;
    const __half*  pWs  = Ws  + (size_t)(g * 64) * U2 + uo;

    for (int t = 0; t < T_STEPS; ++t) {
        if (tid < S2) ibuf[tid] = fmaf(hb[t * S2 + tid], c_iw, c_ib);
        __syncthreads();

        {   // sensory partials: 64 streamed pairs/thread
            float an = 0.f, ad = 0.f;
            #pragma unroll 4
            for (int jj = 0; jj < 16; ++jj) {
                float4 iv = *reinterpret_cast<const float4*>(&ibuf[g * 64 + jj * 4]);
                float vals[4] = {iv.x, iv.y, iv.z, iv.w};
                #pragma unroll
                for (int q = 0; q < 4; ++q) {
                    int j = jj * 4 + q;
                    __half2 ab = pABs[(size_t)j * U2];
                    float a  = __low2float(ab);
                    float bb = __high2float(ab);
                    float ww = __half2float(pWs[(size_t)j * U2]);
                    float e = fast_exp2(bb - a * vals[q]);
                    float r = fast_rcp(1.f + e);
                    an = fmaf(ww, r, an);
                    ad = fmaf(fabsf(ww), r, ad);
                }
            }
            red[g][uo] = make_float2(an, ad);
        }
        __syncthreads();
        if (tid < U2) {
            float2 r0 = red[0][tid], r1 = red[1][tid];
            nbs[tid] = c_nb + r0.x + r1.x;
            dbs[tid] = c_db + r0.y + r1.y;
        }
        __syncthreads();

        for (int k = 0; k < NUNF; ++k) {
            float an = 0.f, ad = 0.f;   // recurrent: 128 cached pairs/thread
            #pragma unroll
            for (int kk = 0; kk < 32; ++kk) {
                float4 vv = *reinterpret_cast<const float4*>(&v2[g * 128 + kk * 4]);
                float vals[4] = {vv.x, vv.y, vv.z, vv.w};
                #pragma unroll
                for (int q = 0; q < 4; ++q) {
                    int j = kk * 4 + q;
                    __half2 ab = cAB[j];
                    __half2 w2 = cW[j >> 1];
                    float a  = __low2float(ab);
                    float bb = __high2float(ab);
                    float ww = (j & 1) ? __high2float(w2) : __low2float(w2);
                    float e = fast_exp2(bb - a * vals[q]);
                    float r = fast_rcp(1.f + e);
                    an = fmaf(ww, r, an);
                    ad = fmaf(fabsf(ww), r, ad);
                }
            }
            red[g][uo] = make_float2(an, ad);
            __syncthreads();
            if (tid < U2) {
                float2 r0 = red[0][tid], r1 = red[1][tid];
                float wn = nbs[tid] + r0.x + r1.x;
                float wd = dbs[tid] + r0.y + r1.y;
                v2[tid] = fmaf(c_cmt, v2[tid], wn) * fast_rcp(wd);
            }
            __syncthreads();
        }
        if (tid < 64) op[t * 64 + tid] = fmaf(v2[tid], c_ow, c_ob);
        __syncthreads();
    }
}

// ---------------------------------------------------------------------------
// FC head: out[b,t,o] = fcb[o] + sum_k h2[b,t,k] * fcw[o,k]
// ---------------------------------------------------------------------------
__global__ __launch_bounds__(512, 1) void fc_head(
    const float* __restrict__ h2, const float* __restrict__ fcw,
    const float* __restrict__ fcb, float* __restrict__ out)
{
    __shared__ float fwT[64 * 64];
    __shared__ float hs[8 * 64];
    const int tid = threadIdx.x;
    for (int i = tid; i < 64 * 64; i += 512) {
        int o = i >> 6, k = i & 63;
        fwT[k * 64 + o] = fcw[i];
    }
    size_t base = (size_t)blockIdx.x * 8 * 64;
    hs[tid] = h2[base + tid];
    __syncthreads();
    const int o = tid & 63, tt = tid >> 6;
    float acc = fcb[o];
    #pragma unroll
    for (int k = 0; k < 64; ++k)
        acc = fmaf(hs[tt * 64 + k], fwT[k * 64 + o], acc);
    out[base + tt * 64 + o] = acc;
}

// ---------------------------------------------------------------------------
extern "C" void kernel_launch(void* const* d_in, const int* in_sizes, int n_in,
                              void* d_out, int out_size, void* d_ws, size_t ws_size,
                              hipStream_t stream)
{
    (void)in_sizes; (void)n_in; (void)out_size; (void)ws_size;

    const float* x      = (const float*)d_in[0];
    const float* l1_iw  = (const float*)d_in[1];
    const float* l1_ib  = (const float*)d_in[2];
    const float* l1_sw  = (const float*)d_in[3];
    const float* l1_ss  = (const float*)d_in[4];
    const float* l1_smu = (const float*)d_in[5];
    const float* l1_se  = (const float*)d_in[6];
    const float* l1_w   = (const float*)d_in[8];
    const float* l1_sg  = (const float*)d_in[9];
    const float* l1_mu  = (const float*)d_in[10];
    const float* l1_er  = (const float*)d_in[11];
    const float* l1_gl  = (const float*)d_in[13];
    const float* l1_vl  = (const float*)d_in[14];
    const float* l1_cm  = (const float*)d_in[15];
    const float* l1_ow  = (const float*)d_in[16];
    const float* l1_ob  = (const float*)d_in[17];
    const float* l2_iw  = (const float*)d_in[18];
    const float* l2_ib  = (const float*)d_in[19];
    const float* l2_sw  = (const float*)d_in[20];
    const float* l2_ss  = (const float*)d_in[21];
    const float* l2_smu = (const float*)d_in[22];
    const float* l2_se  = (const float*)d_in[23];
    const float* l2_w   = (const float*)d_in[25];
    const float* l2_sg  = (const float*)d_in[26];
    const float* l2_mu  = (const float*)d_in[27];
    const float* l2_er  = (const float*)d_in[28];
    const float* l2_gl  = (const float*)d_in[30];
    const float* l2_vl  = (const float*)d_in[31];
    const float* l2_cm  = (const float*)d_in[32];
    const float* l2_ow  = (const float*)d_in[33];
    const float* l2_ob  = (const float*)d_in[34];
    const float* fcw    = (const float*)d_in[35];
    const float* fcb    = (const float*)d_in[36];

    char*  base = (char*)d_ws;
    size_t off  = 0;
    auto alloc = [&](size_t bytes) -> char* {
        char* p = base + off;
        off += (bytes + 255) & ~(size_t)255;
        return p;
    };

    float*   h1   = (float*)  alloc((size_t)B_SZ * T_STEPS * U1 * 4);
    float*   h2   = (float*)  alloc((size_t)B_SZ * T_STEPS * 64 * 4);
    __half2* AB1s = (__half2*)alloc((size_t)S1 * U1 * 4);
    __half*  W1s  = (__half*) alloc((size_t)S1 * U1 * 2);
    __half2* AB1r = (__half2*)alloc((size_t)U1 * U1 * 4);
    __half*  W1r  = (__half*) alloc((size_t)U1 * U1 * 2);
    __half2* AB2s = (__half2*)alloc((size_t)S2 * U2 * 4);
    __half*  W2s  = (__half*) alloc((size_t)S2 * U2 * 2);
    __half2* AB2r = (__half2*)alloc((size_t)U2 * U2 * 4);
    __half*  W2r  = (__half*) alloc((size_t)U2 * U2 * 2);
    float*   cmt1 = (float*)  alloc(U1 * 4);
    float*   nb1  = (float*)  alloc(U1 * 4);
    float*   db1  = (float*)  alloc(U1 * 4);
    float*   cmt2 = (float*)  alloc(U2 * 4);
    float*   nb2  = (float*)  alloc(U2 * 4);
    float*   db2  = (float*)  alloc(U2 * 4);

    prep_half<<<(S1 * U1 + 255) / 256, 256, 0, stream>>>(l1_ss, l1_smu, l1_sw, l1_se, AB1s, W1s, S1 * U1);
    prep_half<<<(U1 * U1 + 255) / 256, 256, 0, stream>>>(l1_sg, l1_mu,  l1_w,  l1_er, AB1r, W1r, U1 * U1);
    prep_half<<<(S2 * U2 + 255) / 256, 256, 0, stream>>>(l2_ss, l2_smu, l2_sw, l2_se, AB2s, W2s, S2 * U2);
    prep_half<<<(U2 * U2 + 255) / 256, 256, 0, stream>>>(l2_sg, l2_mu,  l2_w,  l2_er, AB2r, W2r, U2 * U2);
    prep_vec<<<1, 256, 0, stream>>>(l1_gl, l1_vl, l1_cm, cmt1, nb1, db1, U1);
    prep_vec<<<1, 256, 0, stream>>>(l2_gl, l2_vl, l2_cm, cmt2, nb2, db2, U2);

    ltc1<<<B_SZ, 512, 0, stream>>>(x, l1_iw, l1_ib, AB1s, W1s, AB1r, W1r,
                                   cmt1, nb1, db1, l1_ow, l1_ob, h1);
    ltc2<<<B_SZ, 512, 0, stream>>>(h1, l2_iw, l2_ib, AB2s, W2s, AB2r, W2r,
                                   cmt2, nb2, db2, l2_ow, l2_ob, h2);
    fc_head<<<B_SZ * T_STEPS / 8, 512, 0, stream>>>(h2, fcw, fcb, (float*)d_out);
}

// Round 6
// 20808.189 us; speedup vs baseline: 6.6162x; 6.6162x over previous
//
#include <hip/hip_runtime.h>
#include <hip/hip_fp16.h>

#define B_SZ    64
#define T_STEPS 512
#define U1      128
#define S1      128
#define U2      256
#define S2      128
#define NUNF    6

__device__ __forceinline__ float fast_exp2(float x) { return __builtin_amdgcn_exp2f(x); }
__device__ __forceinline__ float fast_rcp(float x)  { return __builtin_amdgcn_rcpf(x); }

// ---------------------------------------------------------------------------
// Param transform, fp16-packed SoA: AB = half2(sigma*log2e, mu*sigma*log2e),
// W = half(w*erev).  sigmoid((v-mu)*sigma) = 1/(1+exp2(B - A*v)); |W| = w*mask.
// ---------------------------------------------------------------------------
__global__ void prep_half(const float* __restrict__ sg, const float* __restrict__ mu,
                          const float* __restrict__ w, const float* __restrict__ er,
                          __half2* __restrict__ AB, __half* __restrict__ W, int n)
{
    int i = blockIdx.x * 256 + threadIdx.x;
    if (i >= n) return;
    const float L2E = 1.4426950408889634f;
    float a = sg[i] * L2E;
    AB[i] = __floats2half2_rn(a, mu[i] * a);
    W[i]  = __float2half_rn(w[i] * er[i]);
}

__global__ void prep_vec(const float* __restrict__ gleak, const float* __restrict__ vleak,
                         const float* __restrict__ cm,
                         float* __restrict__ cmt, float* __restrict__ nb,
                         float* __restrict__ db, int n)
{
    int i = blockIdx.x * 256 + threadIdx.x;
    if (i >= n) return;
    float c6 = cm[i] * 6.f;
    float gl = gleak[i];
    cmt[i] = c6;
    nb[i]  = gl * vleak[i];
    db[i]  = c6 + gl + 1e-8f;
}

// ---------------------------------------------------------------------------
// Layer 1 sequential: S=128, U=128. 1024 threads: uo=tid&127, g=tid>>7
// (8 groups x 16 inputs).  ALL recurrent params LDS-resident (96 KB);
// sensory params streamed from L2 (1 of 7 passes).
// ---------------------------------------------------------------------------
__global__ __launch_bounds__(1024, 1) void ltc1(
    const float* __restrict__ x,
    const float* __restrict__ in_w, const float* __restrict__ in_b,
    const __half2* __restrict__ ABs, const __half* __restrict__ Ws,
    const __half2* __restrict__ ABr, const __half* __restrict__ Wr,
    const float* __restrict__ cmt, const float* __restrict__ nbv, const float* __restrict__ dbv,
    const float* __restrict__ ow, const float* __restrict__ ob,
    float* __restrict__ h1)
{
    const int b   = blockIdx.x;
    const int tid = threadIdx.x;
    const int uo  = tid & (U1 - 1);
    const int g   = tid >> 7;               // 0..7, 16 inputs each

    __shared__ float   v1[U1];
    __shared__ float   ibuf[S1];
    __shared__ float2  red[8][U1];
    __shared__ float   nbs[U1], dbs[U1];
    __shared__ __half2 ABl[U1 * U1];        // [s][uo], 64 KB
    __shared__ __half2 Wl[(U1 / 2) * U1];   // [s/2][uo] packed (W[s],W[s+1]), 32 KB

    // ---- preload recurrent params into LDS (t-invariant) ----
    for (int idx = tid; idx < U1 * U1; idx += 1024) ABl[idx] = ABr[idx];
    for (int idx = tid; idx < (U1 / 2) * U1; idx += 1024) {
        int u = idx & (U1 - 1), m = idx >> 7;
        Wl[idx] = __halves2half2(Wr[(size_t)(2 * m) * U1 + u],
                                 Wr[(size_t)(2 * m + 1) * U1 + u]);
    }

    float c_cmt = 0, c_nb = 0, c_db = 0, c_iw = 0, c_ib = 0, c_ow = 0, c_ob = 0;
    if (tid < U1) {
        v1[tid] = 0.f;
        c_cmt = cmt[tid]; c_nb = nbv[tid]; c_db = dbv[tid];
        c_iw = in_w[tid]; c_ib = in_b[tid];
        c_ow = ow[tid];   c_ob = ob[tid];
    }
    const float* xb = x  + (size_t)b * T_STEPS * S1;
    float*       hb = h1 + (size_t)b * T_STEPS * U1;

    const __half2* pABs = ABs + (size_t)(g * 16) * U1 + uo;
    const __half*  pWs  = Ws  + (size_t)(g * 16) * U1 + uo;
    __syncthreads();

    for (int t = 0; t < T_STEPS; ++t) {
        if (tid < S1) ibuf[tid] = fmaf(xb[t * S1 + tid], c_iw, c_ib);
        __syncthreads();

        {   // sensory partials: 16 streamed pairs/thread
            float an = 0.f, ad = 0.f;
            #pragma unroll
            for (int jj = 0; jj < 4; ++jj) {
                float4 iv = *reinterpret_cast<const float4*>(&ibuf[g * 16 + jj * 4]);
                float vals[4] = {iv.x, iv.y, iv.z, iv.w};
                #pragma unroll
                for (int q = 0; q < 4; ++q) {
                    int j = jj * 4 + q;
                    __half2 ab = pABs[(size_t)j * U1];
                    float a  = __low2float(ab);
                    float bb = __high2float(ab);
                    float ww = __half2float(pWs[(size_t)j * U1]);
                    float e = fast_exp2(bb - a * vals[q]);
                    float r = fast_rcp(1.f + e);
                    an = fmaf(ww, r, an);
                    ad = fmaf(fabsf(ww), r, ad);
                }
            }
            red[g][uo] = make_float2(an, ad);
        }
        __syncthreads();
        if (tid < U1) {
            float sn = c_nb, sd = c_db;
            #pragma unroll
            for (int gg = 0; gg < 8; ++gg) { float2 r = red[gg][tid]; sn += r.x; sd += r.y; }
            nbs[tid] = sn; dbs[tid] = sd;
        }
        __syncthreads();

        for (int k = 0; k < NUNF; ++k) {
            float an = 0.f, ad = 0.f;   // 16 LDS-resident pairs/thread
            #pragma unroll
            for (int jj = 0; jj < 4; ++jj) {
                float4 vv = *reinterpret_cast<const float4*>(&v1[g * 16 + jj * 4]);
                float vals[4] = {vv.x, vv.y, vv.z, vv.w};
                #pragma unroll
                for (int q = 0; q < 4; ++q) {
                    int j = jj * 4 + q;
                    __half2 ab = ABl[(g * 16 + j) * U1 + uo];
                    __half2 w2 = Wl[(g * 8 + (j >> 1)) * U1 + uo];
                    float a  = __low2float(ab);
                    float bb = __high2float(ab);
                    float ww = (j & 1) ? __high2float(w2) : __low2float(w2);
                    float e = fast_exp2(bb - a * vals[q]);
                    float r = fast_rcp(1.f + e);
                    an = fmaf(ww, r, an);
                    ad = fmaf(fabsf(ww), r, ad);
                }
            }
            red[g][uo] = make_float2(an, ad);
            __syncthreads();
            if (tid < U1) {
                float sn = nbs[tid], sd = dbs[tid];
                #pragma unroll
                for (int gg = 0; gg < 8; ++gg) { float2 r = red[gg][tid]; sn += r.x; sd += r.y; }
                v1[tid] = fmaf(c_cmt, v1[tid], sn) * fast_rcp(sd);
            }
            __syncthreads();
        }
        if (tid < U1) hb[t * U1 + tid] = fmaf(v1[tid], c_ow, c_ob);
    }
}

// ---------------------------------------------------------------------------
// Layer-2 sensory sums, fully parallel over (b,t): 256 CUs busy.
// Block 256 threads = 256 output units, 4 timesteps per block (param reuse).
// ---------------------------------------------------------------------------
__global__ __launch_bounds__(256, 4) void sens2k(
    const float* __restrict__ h1,
    const float* __restrict__ in_w, const float* __restrict__ in_b,
    const __half2* __restrict__ ABs, const __half* __restrict__ Ws,
    float* __restrict__ sn, float* __restrict__ sd)
{
    const int tid = threadIdx.x;
    const int b   = blockIdx.x >> 7;        // T/4 = 128 blocks per batch
    const int t0  = (blockIdx.x & 127) << 2;

    __shared__ float ibu[4][S2];
    for (int idx = tid; idx < 4 * S2; idx += 256) {
        int tt = idx >> 7, s = idx & (S2 - 1);
        ibu[tt][s] = fmaf(h1[((size_t)b * T_STEPS + t0 + tt) * S2 + s], in_w[s], in_b[s]);
    }
    __syncthreads();

    const int u = tid;
    float an0 = 0, an1 = 0, an2 = 0, an3 = 0;
    float ad0 = 0, ad1 = 0, ad2 = 0, ad3 = 0;
    for (int s = 0; s < S2; ++s) {
        __half2 ab = ABs[(size_t)s * U2 + u];
        float a  = __low2float(ab);
        float bb = __high2float(ab);
        float ww = __half2float(Ws[(size_t)s * U2 + u]);
        float aw = fabsf(ww);
        float r0 = fast_rcp(1.f + fast_exp2(bb - a * ibu[0][s]));
        float r1 = fast_rcp(1.f + fast_exp2(bb - a * ibu[1][s]));
        float r2 = fast_rcp(1.f + fast_exp2(bb - a * ibu[2][s]));
        float r3 = fast_rcp(1.f + fast_exp2(bb - a * ibu[3][s]));
        an0 = fmaf(ww, r0, an0); ad0 = fmaf(aw, r0, ad0);
        an1 = fmaf(ww, r1, an1); ad1 = fmaf(aw, r1, ad1);
        an2 = fmaf(ww, r2, an2); ad2 = fmaf(aw, r2, ad2);
        an3 = fmaf(ww, r3, an3); ad3 = fmaf(aw, r3, ad3);
    }
    size_t base = ((size_t)b * T_STEPS + t0) * U2 + u;
    sn[base]           = an0; sd[base]           = ad0;
    sn[base + U2]      = an1; sd[base + U2]      = ad1;
    sn[base + 2 * U2]  = an2; sd[base + 2 * U2]  = ad2;
    sn[base + 3 * U2]  = an3; sd[base + 3 * U2]  = ad3;
}

// ---------------------------------------------------------------------------
// Layer 2 sequential: S=128, U=256. 1024 threads: uo=tid&255, g=tid>>8
// (4 groups x 64 recurrent inputs).  16 of 64 rows/group LDS-resident,
// 48 streamed from L2.  HOIST: sensory sums precomputed by sens2k.
// ---------------------------------------------------------------------------
template <bool HOIST>
__global__ __launch_bounds__(1024, 1) void ltc2(
    const float* __restrict__ h1,
    const float* __restrict__ in_w, const float* __restrict__ in_b,
    const __half2* __restrict__ ABs, const __half* __restrict__ Ws,
    const __half2* __restrict__ ABr, const __half* __restrict__ Wr,
    const float* __restrict__ sn, const float* __restrict__ sd,
    const float* __restrict__ cmt, const float* __restrict__ nbv, const float* __restrict__ dbv,
    const float* __restrict__ ow, const float* __restrict__ ob,
    float* __restrict__ h2)                      // [64][512][64]
{
    const int b   = blockIdx.x;
    const int tid = threadIdx.x;
    const int uo  = tid & (U2 - 1);
    const int g   = tid >> 8;               // 0..3, 64 recurrent inputs each

    __shared__ float   v2[U2];
    __shared__ float   ibuf[S2];
    __shared__ float2  red[4][U2];
    __shared__ float   nbs[U2], dbs[U2];
    __shared__ __half2 ABl[4 * 16 * U2];    // rows g*64+0..15, 64 KB
    __shared__ __half2 Wl[4 * 8 * U2];      // packed W pairs, 32 KB

    // ---- preload the LDS-resident recurrent rows ----
    for (int idx = tid; idx < 4 * 16 * U2; idx += 1024) {
        int u = idx & (U2 - 1), j = (idx >> 8) & 15, gg = idx >> 12;
        ABl[idx] = ABr[(size_t)(gg * 64 + j) * U2 + u];
    }
    for (int idx = tid; idx < 4 * 8 * U2; idx += 1024) {
        int u = idx & (U2 - 1), m = (idx >> 8) & 7, gg = idx >> 11;
        int s0 = gg * 64 + 2 * m;
        Wl[idx] = __halves2half2(Wr[(size_t)s0 * U2 + u], Wr[(size_t)(s0 + 1) * U2 + u]);
    }

    float c_cmt = 0, c_nb = 0, c_db = 0;
    if (tid < U2) {
        v2[tid] = 0.f;
        c_cmt = cmt[tid]; c_nb = nbv[tid]; c_db = dbv[tid];
    }
    float c_iw = 0, c_ib = 0;
    if (tid < S2) { c_iw = in_w[tid]; c_ib = in_b[tid]; }
    float c_ow = 0, c_ob = 0;
    if (tid < 64) { c_ow = ow[tid]; c_ob = ob[tid]; }

    const float* hb = h1 + (size_t)b * T_STEPS * S2;
    float*       op = h2 + (size_t)b * T_STEPS * 64;

    const __half2* pABr = ABr + (size_t)(g * 64) * U2 + uo;   // +j*U2 for j=16..63
    const __half*  pWr  = Wr  + (size_t)(g * 64) * U2 + uo;
    const __half2* pABs = ABs + (size_t)(g * 32) * U2 + uo;   // !HOIST path
    const __half*  pWs  = Ws  + (size_t)(g * 32) * U2 + uo;
    __syncthreads();

    for (int t = 0; t < T_STEPS; ++t) {
        if (HOIST) {
            if (tid < U2) {
                size_t ro = ((size_t)b * T_STEPS + t) * U2 + tid;
                nbs[tid] = c_nb + sn[ro];
                dbs[tid] = c_db + sd[ro];
            }
            __syncthreads();
        } else {
            if (tid < S2) ibuf[tid] = fmaf(hb[t * S2 + tid], c_iw, c_ib);
            __syncthreads();
            float an = 0.f, ad = 0.f;     // 32 streamed sensory pairs/thread
            #pragma unroll 4
            for (int jj = 0; jj < 8; ++jj) {
                float4 iv = *reinterpret_cast<const float4*>(&ibuf[g * 32 + jj * 4]);
                float vals[4] = {iv.x, iv.y, iv.z, iv.w};
                #pragma unroll
                for (int q = 0; q < 4; ++q) {
                    int j = jj * 4 + q;
                    __half2 ab = pABs[(size_t)j * U2];
                    float a  = __low2float(ab);
                    float bb = __high2float(ab);
                    float ww = __half2float(pWs[(size_t)j * U2]);
                    float e = fast_exp2(bb - a * vals[q]);
                    float r = fast_rcp(1.f + e);
                    an = fmaf(ww, r, an);
                    ad = fmaf(fabsf(ww), r, ad);
                }
            }
            red[g][uo] = make_float2(an, ad);
            __syncthreads();
            if (tid < U2) {
                float2 r0 = red[0][tid], r1 = red[1][tid], r2 = red[2][tid], r3 = red[3][tid];
                nbs[tid] = c_nb + ((r0.x + r1.x) + (r2.x + r3.x));
                dbs[tid] = c_db + ((r0.y + r1.y) + (r2.y + r3.y));
            }
            __syncthreads();
        }

        for (int k = 0; k < NUNF; ++k) {
            float an = 0.f, ad = 0.f;
            const int vbase = g * 64;
            // 16 LDS-resident rows
            #pragma unroll
            for (int jj = 0; jj < 4; ++jj) {
                float4 vv = *reinterpret_cast<const float4*>(&v2[vbase + jj * 4]);
                float vals[4] = {vv.x, vv.y, vv.z, vv.w};
                #pragma unroll
                for (int q = 0; q < 4; ++q) {
                    int j = jj * 4 + q;
                    __half2 ab = ABl[(g * 16 + j) * U2 + uo];
                    __half2 w2 = Wl[(g * 8 + (j >> 1)) * U2 + uo];
                    float a  = __low2float(ab);
                    float bb = __high2float(ab);
                    float ww = (j & 1) ? __high2float(w2) : __low2float(w2);
                    float e = fast_exp2(bb - a * vals[q]);
                    float r = fast_rcp(1.f + e);
                    an = fmaf(ww, r, an);
                    ad = fmaf(fabsf(ww), r, ad);
                }
            }
            // 48 L2-streamed rows
            #pragma unroll 4
            for (int jj = 4; jj < 16; ++jj) {
                float4 vv = *reinterpret_cast<const float4*>(&v2[vbase + jj * 4]);
                float vals[4] = {vv.x, vv.y, vv.z, vv.w};
                #pragma unroll
                for (int q = 0; q < 4; ++q) {
                    int j = jj * 4 + q;
                    __half2 ab = pABr[(size_t)j * U2];
                    float a  = __low2float(ab);
                    float bb = __high2float(ab);
                    float ww = __half2float(pWr[(size_t)j * U2]);
                    float e = fast_exp2(bb - a * vals[q]);
                    float r = fast_rcp(1.f + e);
                    an = fmaf(ww, r, an);
                    ad = fmaf(fabsf(ww), r, ad);
                }
            }
            red[g][uo] = make_float2(an, ad);
            __syncthreads();
            if (tid < U2) {
                float2 r0 = red[0][tid], r1 = red[1][tid], r2 = red[2][tid], r3 = red[3][tid];
                float wn = nbs[tid] + ((r0.x + r1.x) + (r2.x + r3.x));
                float wd = dbs[tid] + ((r0.y + r1.y) + (r2.y + r3.y));
                v2[tid] = fmaf(c_cmt, v2[tid], wn) * fast_rcp(wd);
            }
            __syncthreads();
        }
        if (tid < 64) op[t * 64 + tid] = fmaf(v2[tid], c_ow, c_ob);
        __syncthreads();
    }
}

// ---------------------------------------------------------------------------
// FC head: out[b,t,o] = fcb[o] + sum_k h2[b,t,k] * fcw[o,k]
// ---------------------------------------------------------------------------
__global__ __launch_bounds__(512, 1) void fc_head(
    const float* __restrict__ h2, const float* __restrict__ fcw,
    const float* __restrict__ fcb, float* __restrict__ out)
{
    __shared__ float fwT[64 * 64];
    __shared__ float hs[8 * 64];
    const int tid = threadIdx.x;
    for (int i = tid; i < 64 * 64; i += 512) {
        int o = i >> 6, k = i & 63;
        fwT[k * 64 + o] = fcw[i];
    }
    size_t base = (size_t)blockIdx.x * 8 * 64;
    hs[tid] = h2[base + tid];
    __syncthreads();
    const int o = tid & 63, tt = tid >> 6;
    float acc = fcb[o];
    #pragma unroll
    for (int k = 0; k < 64; ++k)
        acc = fmaf(hs[tt * 64 + k], fwT[k * 64 + o], acc);
    out[base + tt * 64 + o] = acc;
}

// ---------------------------------------------------------------------------
extern "C" void kernel_launch(void* const* d_in, const int* in_sizes, int n_in,
                              void* d_out, int out_size, void* d_ws, size_t ws_size,
                              hipStream_t stream)
{
    (void)in_sizes; (void)n_in; (void)out_size;

    const float* x      = (const float*)d_in[0];
    const float* l1_iw  = (const float*)d_in[1];
    const float* l1_ib  = (const float*)d_in[2];
    const float* l1_ss  = (const float*)d_in[4];
    const float* l1_smu = (const float*)d_in[5];
    const float* l1_sw  = (const float*)d_in[3];
    const float* l1_se  = (const float*)d_in[6];
    const float* l1_w   = (const float*)d_in[8];
    const float* l1_sg  = (const float*)d_in[9];
    const float* l1_mu  = (const float*)d_in[10];
    const float* l1_er  = (const float*)d_in[11];
    const float* l1_gl  = (const float*)d_in[13];
    const float* l1_vl  = (const float*)d_in[14];
    const float* l1_cm  = (const float*)d_in[15];
    const float* l1_ow  = (const float*)d_in[16];
    const float* l1_ob  = (const float*)d_in[17];
    const float* l2_iw  = (const float*)d_in[18];
    const float* l2_ib  = (const float*)d_in[19];
    const float* l2_sw  = (const float*)d_in[20];
    const float* l2_ss  = (const float*)d_in[21];
    const float* l2_smu = (const float*)d_in[22];
    const float* l2_se  = (const float*)d_in[23];
    const float* l2_w   = (const float*)d_in[25];
    const float* l2_sg  = (const float*)d_in[26];
    const float* l2_mu  = (const float*)d_in[27];
    const float* l2_er  = (const float*)d_in[28];
    const float* l2_gl  = (const float*)d_in[30];
    const float* l2_vl  = (const float*)d_in[31];
    const float* l2_cm  = (const float*)d_in[32];
    const float* l2_ow  = (const float*)d_in[33];
    const float* l2_ob  = (const float*)d_in[34];
    const float* fcw    = (const float*)d_in[35];
    const float* fcb    = (const float*)d_in[36];

    char*  base = (char*)d_ws;
    size_t off  = 0;
    auto alloc = [&](size_t bytes) -> char* {
        char* p = base + off;
        off += (bytes + 255) & ~(size_t)255;
        return p;
    };

    float*   h1   = (float*)  alloc((size_t)B_SZ * T_STEPS * U1 * 4);
    float*   h2   = (float*)  alloc((size_t)B_SZ * T_STEPS * 64 * 4);
    __half2* AB1s = (__half2*)alloc((size_t)S1 * U1 * 4);
    __half*  W1s  = (__half*) alloc((size_t)S1 * U1 * 2);
    __half2* AB1r = (__half2*)alloc((size_t)U1 * U1 * 4);
    __half*  W1r  = (__half*) alloc((size_t)U1 * U1 * 2);
    __half2* AB2s = (__half2*)alloc((size_t)S2 * U2 * 4);
    __half*  W2s  = (__half*) alloc((size_t)S2 * U2 * 2);
    __half2* AB2r = (__half2*)alloc((size_t)U2 * U2 * 4);
    __half*  W2r  = (__half*) alloc((size_t)U2 * U2 * 2);
    float*   cmt1 = (float*)  alloc(U1 * 4);
    float*   nb1  = (float*)  alloc(U1 * 4);
    float*   db1  = (float*)  alloc(U1 * 4);
    float*   cmt2 = (float*)  alloc(U2 * 4);
    float*   nb2  = (float*)  alloc(U2 * 4);
    float*   db2  = (float*)  alloc(U2 * 4);

    // sensory-hoist buffers (67 MB) — only if workspace is large enough
    size_t sens_bytes = (size_t)B_SZ * T_STEPS * U2 * 4;
    bool hoist = (off + 2 * sens_bytes + 512) <= ws_size;
    float* sn2 = nullptr; float* sd2 = nullptr;
    if (hoist) {
        sn2 = (float*)alloc(sens_bytes);
        sd2 = (float*)alloc(sens_bytes);
    }

    prep_half<<<(S1 * U1 + 255) / 256, 256, 0, stream>>>(l1_ss, l1_smu, l1_sw, l1_se, AB1s, W1s, S1 * U1);
    prep_half<<<(U1 * U1 + 255) / 256, 256, 0, stream>>>(l1_sg, l1_mu,  l1_w,  l1_er, AB1r, W1r, U1 * U1);
    prep_half<<<(S2 * U2 + 255) / 256, 256, 0, stream>>>(l2_ss, l2_smu, l2_sw, l2_se, AB2s, W2s, S2 * U2);
    prep_half<<<(U2 * U2 + 255) / 256, 256, 0, stream>>>(l2_sg, l2_mu,  l2_w,  l2_er, AB2r, W2r, U2 * U2);
    prep_vec<<<1, 256, 0, stream>>>(l1_gl, l1_vl, l1_cm, cmt1, nb1, db1, U1);
    prep_vec<<<1, 256, 0, stream>>>(l2_gl, l2_vl, l2_cm, cmt2, nb2, db2, U2);

    ltc1<<<B_SZ, 1024, 0, stream>>>(x, l1_iw, l1_ib, AB1s, W1s, AB1r, W1r,
                                    cmt1, nb1, db1, l1_ow, l1_ob, h1);

    if (hoist) {
        sens2k<<<B_SZ * (T_STEPS / 4), 256, 0, stream>>>(h1, l2_iw, l2_ib, AB2s, W2s, sn2, sd2);
        ltc2<true><<<B_SZ, 1024, 0, stream>>>(h1, l2_iw, l2_ib, AB2s, W2s, AB2r, W2r,
                                              sn2, sd2, cmt2, nb2, db2, l2_ow, l2_ob, h2);
    } else {
        ltc2<false><<<B_SZ, 1024, 0, stream>>>(h1, l2_iw, l2_ib, AB2s, W2s, AB2r, W2r,
                                               nullptr, nullptr, cmt2, nb2, db2, l2_ow, l2_ob, h2);
    }
    fc_head<<<B_SZ * T_STEPS / 8, 512, 0, stream>>>(h2, fcw, fcb, (float*)d_out);
}

// Round 7
// 20754.524 us; speedup vs baseline: 6.6333x; 1.0026x over previous
//
#include <hip/hip_runtime.h>
#include <hip/hip_fp16.h>

#define B_SZ    64
#define T_STEPS 512
#define U1      128
#define S1      128
#define U2      256
#define S2      128
#define NUNF    6
#define RC2     6       // ltc2: LDS-resident chunks (of 16) per group

__device__ __forceinline__ float fast_exp2(float x) { return __builtin_amdgcn_exp2f(x); }
__device__ __forceinline__ float fast_rcp(float x)  { return __builtin_amdgcn_rcpf(x); }
__device__ __forceinline__ __half2 bits2h2(unsigned u) { return *reinterpret_cast<__half2*>(&u); }

// ---------------------------------------------------------------------------
// eval 4 synapse pairs from one packed chunk.
// ab4 = 4x half2(A=sigma*log2e, B=mu*sigma*log2e); w2 = 4x half(W=w*erev).
// sigmoid((v-mu)*sigma) = 1/(1+exp2(B - A*v)); |W| = w*mask (w>0).
// ---------------------------------------------------------------------------
__device__ __forceinline__ void eval4(uint4 ab4, uint2 w2, float4 vv,
                                      float& an, float& ad)
{
    const unsigned abq[4] = {ab4.x, ab4.y, ab4.z, ab4.w};
    const float vals[4] = {vv.x, vv.y, vv.z, vv.w};
    #pragma unroll
    for (int q = 0; q < 4; ++q) {
        __half2 ab = bits2h2(abq[q]);
        __half2 wp = bits2h2((q < 2) ? w2.x : w2.y);
        float a  = __low2float(ab);
        float bb = __high2float(ab);
        float ww = (q & 1) ? __high2float(wp) : __low2float(wp);
        float e = fast_exp2(bb - a * vals[q]);
        float r = fast_rcp(1.f + e);
        an = fmaf(ww, r, an);
        ad = fmaf(fabsf(ww), r, ad);
    }
}

// ---------------------------------------------------------------------------
// prep: chunked packing. i indexes (s4, uo); rows s = s4*4+q.
// ---------------------------------------------------------------------------
__global__ void prep_chunk(const float* __restrict__ sg, const float* __restrict__ mu,
                           const float* __restrict__ w, const float* __restrict__ er,
                           uint4* __restrict__ AB4, uint2* __restrict__ W2, int S4, int U)
{
    int i = blockIdx.x * 256 + threadIdx.x;
    if (i >= S4 * U) return;
    int uo = i % U, s4 = i / U;
    const float L2E = 1.4426950408889634f;
    unsigned ab[4]; __half wh[4];
    #pragma unroll
    for (int q = 0; q < 4; ++q) {
        size_t idx = (size_t)(s4 * 4 + q) * U + uo;
        float a = sg[idx] * L2E;
        __half2 h = __floats2half2_rn(a, mu[idx] * a);
        ab[q] = *reinterpret_cast<unsigned*>(&h);
        wh[q] = __float2half_rn(w[idx] * er[idx]);
    }
    __half2 w01 = __halves2half2(wh[0], wh[1]);
    __half2 w23 = __halves2half2(wh[2], wh[3]);
    AB4[i] = make_uint4(ab[0], ab[1], ab[2], ab[3]);
    W2[i]  = make_uint2(*reinterpret_cast<unsigned*>(&w01),
                        *reinterpret_cast<unsigned*>(&w23));
}

// linear fp16 pack (sens2k + ltc2 fallback path)
__global__ void prep_half(const float* __restrict__ sg, const float* __restrict__ mu,
                          const float* __restrict__ w, const float* __restrict__ er,
                          __half2* __restrict__ AB, __half* __restrict__ W, int n)
{
    int i = blockIdx.x * 256 + threadIdx.x;
    if (i >= n) return;
    const float L2E = 1.4426950408889634f;
    float a = sg[i] * L2E;
    AB[i] = __floats2half2_rn(a, mu[i] * a);
    W[i]  = __float2half_rn(w[i] * er[i]);
}

__global__ void prep_vec(const float* __restrict__ gleak, const float* __restrict__ vleak,
                         const float* __restrict__ cm,
                         float* __restrict__ cmt, float* __restrict__ nb,
                         float* __restrict__ db, int n)
{
    int i = blockIdx.x * 256 + threadIdx.x;
    if (i >= n) return;
    float c6 = cm[i] * 6.f;
    float gl = gleak[i];
    cmt[i] = c6;
    nb[i]  = gl * vleak[i];
    db[i]  = c6 + gl + 1e-8f;
}

// ---------------------------------------------------------------------------
// Layer 1: S=128, U=128. 1024 thr: uo=tid&127, g=tid>>7 (8 groups x 16 rows
// = 4 chunks).  ALL recurrent chunks LDS-resident; sensory chunks streamed.
// ---------------------------------------------------------------------------
__global__ __launch_bounds__(1024, 1) void ltc1(
    const float* __restrict__ x,
    const float* __restrict__ in_w, const float* __restrict__ in_b,
    const uint4* __restrict__ AB4s, const uint2* __restrict__ W2s,
    const uint4* __restrict__ AB4r, const uint2* __restrict__ W2r,
    const float* __restrict__ cmt, const float* __restrict__ nbv, const float* __restrict__ dbv,
    const float* __restrict__ ow, const float* __restrict__ ob,
    float* __restrict__ h1)
{
    const int b   = blockIdx.x;
    const int tid = threadIdx.x;
    const int uo  = tid & (U1 - 1);
    const int g   = tid >> 7;

    __shared__ float  v1[U1], ibuf[S1], nbs[U1], dbs[U1];
    __shared__ float2 red[8][U1];
    __shared__ uint4  AB4l[32 * U1];    // 64 KB
    __shared__ uint2  W2l[32 * U1];     // 32 KB

    for (int idx = tid; idx < 32 * U1; idx += 1024) {
        AB4l[idx] = AB4r[idx];
        W2l[idx]  = W2r[idx];
    }

    float c_cmt = 0, c_nb = 0, c_db = 0, c_iw = 0, c_ib = 0, c_ow = 0, c_ob = 0;
    if (tid < U1) {
        v1[tid] = 0.f;
        c_cmt = cmt[tid]; c_nb = nbv[tid]; c_db = dbv[tid];
        c_iw = in_w[tid]; c_ib = in_b[tid];
        c_ow = ow[tid];   c_ob = ob[tid];
    }
    const float* xb = x  + (size_t)b * T_STEPS * S1;
    float*       hb = h1 + (size_t)b * T_STEPS * U1;
    __syncthreads();

    for (int t = 0; t < T_STEPS; ++t) {
        if (tid < S1) ibuf[tid] = fmaf(xb[t * S1 + tid], c_iw, c_ib);
        __syncthreads();

        {   // sensory: 4 streamed chunks
            float an = 0.f, ad = 0.f;
            #pragma unroll 2
            for (int c = 0; c < 4; ++c) {
                uint4 ab = AB4s[(g * 4 + c) * U1 + uo];
                uint2 w2 = W2s[(g * 4 + c) * U1 + uo];
                float4 vv = *reinterpret_cast<const float4*>(&ibuf[g * 16 + c * 4]);
                eval4(ab, w2, vv, an, ad);
            }
            red[g][uo] = make_float2(an, ad);
        }
        __syncthreads();
        if (tid < U1) {
            float sn = c_nb, sd = c_db;
            #pragma unroll
            for (int gg = 0; gg < 8; ++gg) { float2 r = red[gg][tid]; sn += r.x; sd += r.y; }
            nbs[tid] = sn; dbs[tid] = sd;
        }
        __syncthreads();

        for (int k = 0; k < NUNF; ++k) {
            float an = 0.f, ad = 0.f;
            #pragma unroll
            for (int c = 0; c < 4; ++c) {
                uint4 ab = AB4l[(g * 4 + c) * U1 + uo];
                uint2 w2 = W2l[(g * 4 + c) * U1 + uo];
                float4 vv = *reinterpret_cast<const float4*>(&v1[g * 16 + c * 4]);
                eval4(ab, w2, vv, an, ad);
            }
            red[g][uo] = make_float2(an, ad);
            __syncthreads();
            if (tid < U1) {
                float sn = nbs[tid], sd = dbs[tid];
                #pragma unroll
                for (int gg = 0; gg < 8; ++gg) { float2 r = red[gg][tid]; sn += r.x; sd += r.y; }
                v1[tid] = fmaf(c_cmt, v1[tid], sn) * fast_rcp(sd);
            }
            __syncthreads();
        }
        if (tid < U1) hb[t * U1 + tid] = fmaf(v1[tid], c_ow, c_ob);
    }
}

// ---------------------------------------------------------------------------
// Layer-2 sensory sums, fully parallel over (b,t).
// ---------------------------------------------------------------------------
__global__ __launch_bounds__(256, 4) void sens2k(
    const float* __restrict__ h1,
    const float* __restrict__ in_w, const float* __restrict__ in_b,
    const __half2* __restrict__ ABs, const __half* __restrict__ Ws,
    float* __restrict__ sn, float* __restrict__ sd)
{
    const int tid = threadIdx.x;
    const int b   = blockIdx.x >> 7;
    const int t0  = (blockIdx.x & 127) << 2;

    __shared__ float ibu[4][S2];
    for (int idx = tid; idx < 4 * S2; idx += 256) {
        int tt = idx >> 7, s = idx & (S2 - 1);
        ibu[tt][s] = fmaf(h1[((size_t)b * T_STEPS + t0 + tt) * S2 + s], in_w[s], in_b[s]);
    }
    __syncthreads();

    const int u = tid;
    float an0 = 0, an1 = 0, an2 = 0, an3 = 0;
    float ad0 = 0, ad1 = 0, ad2 = 0, ad3 = 0;
    for (int s = 0; s < S2; ++s) {
        __half2 ab = ABs[(size_t)s * U2 + u];
        float a  = __low2float(ab);
        float bb = __high2float(ab);
        float ww = __half2float(Ws[(size_t)s * U2 + u]);
        float aw = fabsf(ww);
        float r0 = fast_rcp(1.f + fast_exp2(bb - a * ibu[0][s]));
        float r1 = fast_rcp(1.f + fast_exp2(bb - a * ibu[1][s]));
        float r2 = fast_rcp(1.f + fast_exp2(bb - a * ibu[2][s]));
        float r3 = fast_rcp(1.f + fast_exp2(bb - a * ibu[3][s]));
        an0 = fmaf(ww, r0, an0); ad0 = fmaf(aw, r0, ad0);
        an1 = fmaf(ww, r1, an1); ad1 = fmaf(aw, r1, ad1);
        an2 = fmaf(ww, r2, an2); ad2 = fmaf(aw, r2, ad2);
        an3 = fmaf(ww, r3, an3); ad3 = fmaf(aw, r3, ad3);
    }
    size_t base = ((size_t)b * T_STEPS + t0) * U2 + u;
    sn[base]          = an0; sd[base]          = ad0;
    sn[base + U2]     = an1; sd[base + U2]     = ad1;
    sn[base + 2 * U2] = an2; sd[base + 2 * U2] = ad2;
    sn[base + 3 * U2] = an3; sd[base + 3 * U2] = ad3;
}

// ---------------------------------------------------------------------------
// Layer 2: S=128, U=256. 1024 thr: uo=tid&255, g=tid>>8 (4 groups x 64 rows
// = 16 chunks).  RC2=6 chunks/group LDS-resident, 10 streamed from L2.
// ---------------------------------------------------------------------------
template <bool HOIST>
__global__ __launch_bounds__(1024, 1) void ltc2(
    const float* __restrict__ h1,
    const float* __restrict__ in_w, const float* __restrict__ in_b,
    const uint4* __restrict__ AB4s, const uint2* __restrict__ W2s,
    const uint4* __restrict__ AB4r, const uint2* __restrict__ W2r,
    const float* __restrict__ sn, const float* __restrict__ sd,
    const float* __restrict__ cmt, const float* __restrict__ nbv, const float* __restrict__ dbv,
    const float* __restrict__ ow, const float* __restrict__ ob,
    float* __restrict__ h2)
{
    const int b   = blockIdx.x;
    const int tid = threadIdx.x;
    const int uo  = tid & (U2 - 1);
    const int g   = tid >> 8;

    __shared__ float  v2[U2], ibuf[S2], nbs[U2], dbs[U2];
    __shared__ float2 red[4][U2];
    __shared__ uint4  AB4l[4 * RC2 * U2];   // 96 KB
    __shared__ uint2  W2l[4 * RC2 * U2];    // 48 KB

    for (int idx = tid; idx < 4 * RC2 * U2; idx += 1024) {
        int uo_ = idx & (U2 - 1);
        int c_  = (idx >> 8) % RC2;
        int g_  = idx / (RC2 * U2);
        size_t src = (size_t)(g_ * 16 + c_) * U2 + uo_;
        AB4l[idx] = AB4r[src];
        W2l[idx]  = W2r[src];
    }

    float c_cmt = 0, c_nb = 0, c_db = 0;
    if (tid < U2) {
        v2[tid] = 0.f;
        c_cmt = cmt[tid]; c_nb = nbv[tid]; c_db = dbv[tid];
    }
    float c_iw = 0, c_ib = 0;
    if (tid < S2) { c_iw = in_w[tid]; c_ib = in_b[tid]; }
    float c_ow = 0, c_ob = 0;
    if (tid < 64) { c_ow = ow[tid]; c_ob = ob[tid]; }

    const float* hb = h1 + (size_t)b * T_STEPS * S2;
    float*       op = h2 + (size_t)b * T_STEPS * 64;
    const uint4* pAB = AB4r + (size_t)(g * 16) * U2 + uo;
    const uint2* pW  = W2r  + (size_t)(g * 16) * U2 + uo;
    __syncthreads();

    for (int t = 0; t < T_STEPS; ++t) {
        if (HOIST) {
            if (tid < U2) {
                size_t ro = ((size_t)b * T_STEPS + t) * U2 + tid;
                nbs[tid] = c_nb + sn[ro];
                dbs[tid] = c_db + sd[ro];
            }
            __syncthreads();
        } else {
            if (tid < S2) ibuf[tid] = fmaf(hb[t * S2 + tid], c_iw, c_ib);
            __syncthreads();
            float an = 0.f, ad = 0.f;   // sensory: 8 streamed chunks/group
            #pragma unroll 2
            for (int c = 0; c < 8; ++c) {
                uint4 ab = AB4s[(size_t)(g * 8 + c) * U2 + uo];
                uint2 w2 = W2s[(size_t)(g * 8 + c) * U2 + uo];
                float4 vv = *reinterpret_cast<const float4*>(&ibuf[g * 32 + c * 4]);
                eval4(ab, w2, vv, an, ad);
            }
            red[g][uo] = make_float2(an, ad);
            __syncthreads();
            if (tid < U2) {
                float2 r0 = red[0][tid], r1 = red[1][tid], r2 = red[2][tid], r3 = red[3][tid];
                nbs[tid] = c_nb + ((r0.x + r1.x) + (r2.x + r3.x));
                dbs[tid] = c_db + ((r0.y + r1.y) + (r2.y + r3.y));
            }
            __syncthreads();
        }

        for (int k = 0; k < NUNF; ++k) {
            float an = 0.f, ad = 0.f;
            // resident chunks
            #pragma unroll
            for (int c = 0; c < RC2; ++c) {
                uint4 ab = AB4l[(g * RC2 + c) * U2 + uo];
                uint2 w2 = W2l[(g * RC2 + c) * U2 + uo];
                float4 vv = *reinterpret_cast<const float4*>(&v2[g * 64 + c * 4]);
                eval4(ab, w2, vv, an, ad);
            }
            // streamed chunks
            #pragma unroll 2
            for (int c = RC2; c < 16; ++c) {
                uint4 ab = pAB[(size_t)c * U2];
                uint2 w2 = pW[(size_t)c * U2];
                float4 vv = *reinterpret_cast<const float4*>(&v2[g * 64 + c * 4]);
                eval4(ab, w2, vv, an, ad);
            }
            red[g][uo] = make_float2(an, ad);
            __syncthreads();
            if (tid < U2) {
                float2 r0 = red[0][tid], r1 = red[1][tid], r2 = red[2][tid], r3 = red[3][tid];
                float wn = nbs[tid] + ((r0.x + r1.x) + (r2.x + r3.x));
                float wd = dbs[tid] + ((r0.y + r1.y) + (r2.y + r3.y));
                v2[tid] = fmaf(c_cmt, v2[tid], wn) * fast_rcp(wd);
            }
            __syncthreads();
        }
        if (tid < 64) op[t * 64 + tid] = fmaf(v2[tid], c_ow, c_ob);
        __syncthreads();
    }
}

// ---------------------------------------------------------------------------
// FC head: out[b,t,o] = fcb[o] + sum_k h2[b,t,k] * fcw[o,k]
// ---------------------------------------------------------------------------
__global__ __launch_bounds__(512, 1) void fc_head(
    const float* __restrict__ h2, const float* __restrict__ fcw,
    const float* __restrict__ fcb, float* __restrict__ out)
{
    __shared__ float fwT[64 * 64];
    __shared__ float hs[8 * 64];
    const int tid = threadIdx.x;
    for (int i = tid; i < 64 * 64; i += 512) {
        int o = i >> 6, k = i & 63;
        fwT[k * 64 + o] = fcw[i];
    }
    size_t base = (size_t)blockIdx.x * 8 * 64;
    hs[tid] = h2[base + tid];
    __syncthreads();
    const int o = tid & 63, tt = tid >> 6;
    float acc = fcb[o];
    #pragma unroll
    for (int k = 0; k < 64; ++k)
        acc = fmaf(hs[tt * 64 + k], fwT[k * 64 + o], acc);
    out[base + tt * 64 + o] = acc;
}

// ---------------------------------------------------------------------------
extern "C" void kernel_launch(void* const* d_in, const int* in_sizes, int n_in,
                              void* d_out, int out_size, void* d_ws, size_t ws_size,
                              hipStream_t stream)
{
    (void)in_sizes; (void)n_in; (void)out_size;

    const float* x      = (const float*)d_in[0];
    const float* l1_iw  = (const float*)d_in[1];
    const float* l1_ib  = (const float*)d_in[2];
    const float* l1_sw  = (const float*)d_in[3];
    const float* l1_ss  = (const float*)d_in[4];
    const float* l1_smu = (const float*)d_in[5];
    const float* l1_se  = (const float*)d_in[6];
    const float* l1_w   = (const float*)d_in[8];
    const float* l1_sg  = (const float*)d_in[9];
    const float* l1_mu  = (const float*)d_in[10];
    const float* l1_er  = (const float*)d_in[11];
    const float* l1_gl  = (const float*)d_in[13];
    const float* l1_vl  = (const float*)d_in[14];
    const float* l1_cm  = (const float*)d_in[15];
    const float* l1_ow  = (const float*)d_in[16];
    const float* l1_ob  = (const float*)d_in[17];
    const float* l2_iw  = (const float*)d_in[18];
    const float* l2_ib  = (const float*)d_in[19];
    const float* l2_sw  = (const float*)d_in[20];
    const float* l2_ss  = (const float*)d_in[21];
    const float* l2_smu = (const float*)d_in[22];
    const float* l2_se  = (const float*)d_in[23];
    const float* l2_w   = (const float*)d_in[25];
    const float* l2_sg  = (const float*)d_in[26];
    const float* l2_mu  = (const float*)d_in[27];
    const float* l2_er  = (const float*)d_in[28];
    const float* l2_gl  = (const float*)d_in[30];
    const float* l2_vl  = (const float*)d_in[31];
    const float* l2_cm  = (const float*)d_in[32];
    const float* l2_ow  = (const float*)d_in[33];
    const float* l2_ob  = (const float*)d_in[34];
    const float* fcw    = (const float*)d_in[35];
    const float* fcb    = (const float*)d_in[36];

    char*  base = (char*)d_ws;
    size_t off  = 0;
    auto alloc = [&](size_t bytes) -> char* {
        char* p = base + off;
        off += (bytes + 255) & ~(size_t)255;
        return p;
    };

    float*   h1   = (float*)  alloc((size_t)B_SZ * T_STEPS * U1 * 4);
    float*   h2   = (float*)  alloc((size_t)B_SZ * T_STEPS * 64 * 4);
    // chunked params
    uint4* AB4s1 = (uint4*)alloc((size_t)(S1/4) * U1 * 16);
    uint2* W2s1  = (uint2*)alloc((size_t)(S1/4) * U1 * 8);
    uint4* AB4r1 = (uint4*)alloc((size_t)(U1/4) * U1 * 16);
    uint2* W2r1  = (uint2*)alloc((size_t)(U1/4) * U1 * 8);
    uint4* AB4s2 = (uint4*)alloc((size_t)(S2/4) * U2 * 16);
    uint2* W2s2  = (uint2*)alloc((size_t)(S2/4) * U2 * 8);
    uint4* AB4r2 = (uint4*)alloc((size_t)(U2/4) * U2 * 16);
    uint2* W2r2  = (uint2*)alloc((size_t)(U2/4) * U2 * 8);
    // linear fp16 (sens2k)
    __half2* AB2s = (__half2*)alloc((size_t)S2 * U2 * 4);
    __half*  W2s  = (__half*) alloc((size_t)S2 * U2 * 2);
    float*   cmt1 = (float*)  alloc(U1 * 4);
    float*   nb1  = (float*)  alloc(U1 * 4);
    float*   db1  = (float*)  alloc(U1 * 4);
    float*   cmt2 = (float*)  alloc(U2 * 4);
    float*   nb2  = (float*)  alloc(U2 * 4);
    float*   db2  = (float*)  alloc(U2 * 4);

    size_t sens_bytes = (size_t)B_SZ * T_STEPS * U2 * 4;
    bool hoist = (off + 2 * sens_bytes + 512) <= ws_size;
    float* sn2 = nullptr; float* sd2 = nullptr;
    if (hoist) {
        sn2 = (float*)alloc(sens_bytes);
        sd2 = (float*)alloc(sens_bytes);
    }

    prep_chunk<<<((S1/4)*U1 + 255)/256, 256, 0, stream>>>(l1_ss, l1_smu, l1_sw, l1_se, AB4s1, W2s1, S1/4, U1);
    prep_chunk<<<((U1/4)*U1 + 255)/256, 256, 0, stream>>>(l1_sg, l1_mu,  l1_w,  l1_er, AB4r1, W2r1, U1/4, U1);
    prep_chunk<<<((S2/4)*U2 + 255)/256, 256, 0, stream>>>(l2_ss, l2_smu, l2_sw, l2_se, AB4s2, W2s2, S2/4, U2);
    prep_chunk<<<((U2/4)*U2 + 255)/256, 256, 0, stream>>>(l2_sg, l2_mu,  l2_w,  l2_er, AB4r2, W2r2, U2/4, U2);
    prep_half<<<(S2 * U2 + 255)/256, 256, 0, stream>>>(l2_ss, l2_smu, l2_sw, l2_se, AB2s, W2s, S2 * U2);
    prep_vec<<<1, 256, 0, stream>>>(l1_gl, l1_vl, l1_cm, cmt1, nb1, db1, U1);
    prep_vec<<<1, 256, 0, stream>>>(l2_gl, l2_vl, l2_cm, cmt2, nb2, db2, U2);

    ltc1<<<B_SZ, 1024, 0, stream>>>(x, l1_iw, l1_ib, AB4s1, W2s1, AB4r1, W2r1,
                                    cmt1, nb1, db1, l1_ow, l1_ob, h1);

    if (hoist) {
        sens2k<<<B_SZ * (T_STEPS / 4), 256, 0, stream>>>(h1, l2_iw, l2_ib, AB2s, W2s, sn2, sd2);
        ltc2<true><<<B_SZ, 1024, 0, stream>>>(h1, l2_iw, l2_ib, AB4s2, W2s2, AB4r2, W2r2,
                                              sn2, sd2, cmt2, nb2, db2, l2_ow, l2_ob, h2);
    } else {
        ltc2<false><<<B_SZ, 1024, 0, stream>>>(h1, l2_iw, l2_ib, AB4s2, W2s2, AB4r2, W2r2,
                                               nullptr, nullptr, cmt2, nb2, db2, l2_ow, l2_ob, h2);
    }
    fc_head<<<B_SZ * T_STEPS / 8, 512, 0, stream>>>(h2, fcw, fcb, (float*)d_out);
}

// Round 9
// 19283.919 us; speedup vs baseline: 7.1392x; 1.0763x over previous
//
#include <hip/hip_runtime.h>
#include <hip/hip_fp16.h>

#define B_SZ    64
#define T_STEPS 512
#define U1      128
#define S1      128
#define U2      256
#define S2      128
#define NUNF    6
#define RC2     6       // ltc2: LDS-resident chunks (of 16) per group

typedef _Float16 h2f __attribute__((ext_vector_type(2)));

__device__ __forceinline__ float fast_exp2(float x) { return __builtin_amdgcn_exp2f(x); }
__device__ __forceinline__ float fast_rcp(float x)  { return __builtin_amdgcn_rcpf(x); }
__device__ __forceinline__ h2f u2h(unsigned u) { union { unsigned x; h2f h; } c; c.x = u; return c.h; }
__device__ __forceinline__ h2f pkrtz(float a, float b)
{
    return __builtin_bit_cast(h2f, __builtin_amdgcn_cvt_pkrtz(a, b));
}

// ---------------------------------------------------------------------------
// eval 4 synapse pairs: AB half2(A=sig*log2e, B=mu*sig*log2e), W half(w*erev).
// sigmoid((v-mu)*sig) = 1/(1+exp2(B-A*v)); |W| = w*mask (w>0).
// r packed to fp16 (pkrtz) and accumulated via v_dot2_f32_f16.
// ---------------------------------------------------------------------------
__device__ __forceinline__ void eval4d(uint4 ab4, uint2 w2, float4 vv,
                                       float& an, float& ad)
{
    h2f ab0 = u2h(ab4.x), ab1 = u2h(ab4.y), ab2 = u2h(ab4.z), ab3 = u2h(ab4.w);
    float r0 = fast_rcp(1.f + fast_exp2(fmaf(-(float)ab0[0], vv.x, (float)ab0[1])));
    float r1 = fast_rcp(1.f + fast_exp2(fmaf(-(float)ab1[0], vv.y, (float)ab1[1])));
    float r2 = fast_rcp(1.f + fast_exp2(fmaf(-(float)ab2[0], vv.z, (float)ab2[1])));
    float r3 = fast_rcp(1.f + fast_exp2(fmaf(-(float)ab3[0], vv.w, (float)ab3[1])));
    h2f rp01 = pkrtz(r0, r1);
    h2f rp23 = pkrtz(r2, r3);
    an = __builtin_amdgcn_fdot2(u2h(w2.x), rp01, an, false);
    an = __builtin_amdgcn_fdot2(u2h(w2.y), rp23, an, false);
    ad = __builtin_amdgcn_fdot2(u2h(w2.x & 0x7FFF7FFFu), rp01, ad, false);
    ad = __builtin_amdgcn_fdot2(u2h(w2.y & 0x7FFF7FFFu), rp23, ad, false);
}

// scalar variant (ltc1 / sens2k numerics, fma-based accumulation)
__device__ __forceinline__ void eval4(uint4 ab4, uint2 w2, float4 vv,
                                      float& an, float& ad)
{
    const unsigned abq[4] = {ab4.x, ab4.y, ab4.z, ab4.w};
    const float vals[4] = {vv.x, vv.y, vv.z, vv.w};
    #pragma unroll
    for (int q = 0; q < 4; ++q) {
        h2f ab = u2h(abq[q]);
        h2f wp = u2h((q < 2) ? w2.x : w2.y);
        float a  = (float)ab[0];
        float bb = (float)ab[1];
        float ww = (float)((q & 1) ? wp[1] : wp[0]);
        float e = fast_exp2(fmaf(-a, vals[q], bb));
        float r = fast_rcp(1.f + e);
        an = fmaf(ww, r, an);
        ad = fmaf(fabsf(ww), r, ad);
    }
}

// ---------------------------------------------------------------------------
// prep: chunked packing, linear layout [s4][u] (ltc1)
// ---------------------------------------------------------------------------
__global__ void prep_chunk(const float* __restrict__ sg, const float* __restrict__ mu,
                           const float* __restrict__ w, const float* __restrict__ er,
                           uint4* __restrict__ AB4, uint2* __restrict__ W2, int S4, int U)
{
    int i = blockIdx.x * 256 + threadIdx.x;
    if (i >= S4 * U) return;
    int uo = i % U, s4 = i / U;
    const float L2E = 1.4426950408889634f;
    unsigned ab[4]; __half wh[4];
    #pragma unroll
    for (int q = 0; q < 4; ++q) {
        size_t idx = (size_t)(s4 * 4 + q) * U + uo;
        float a = sg[idx] * L2E;
        __half2 h = __floats2half2_rn(a, mu[idx] * a);
        ab[q] = *reinterpret_cast<unsigned*>(&h);
        wh[q] = __float2half_rn(w[idx] * er[idx]);
    }
    __half2 w01 = __halves2half2(wh[0], wh[1]);
    __half2 w23 = __halves2half2(wh[2], wh[3]);
    AB4[i] = make_uint4(ab[0], ab[1], ab[2], ab[3]);
    W2[i]  = make_uint2(*reinterpret_cast<unsigned*>(&w01),
                        *reinterpret_cast<unsigned*>(&w23));
}

// prep: chunked packing, interleaved layout [c][u][g] for the butterfly kernel.
// s4 = g*CPG + c  ->  out index (c*U + u)*4 + g.
__global__ void prep_ilv(const float* __restrict__ sg, const float* __restrict__ mu,
                         const float* __restrict__ w, const float* __restrict__ er,
                         uint4* __restrict__ ABI, uint2* __restrict__ WI, int S4, int U, int CPG)
{
    int i = blockIdx.x * 256 + threadIdx.x;
    if (i >= S4 * U) return;
    int uo = i % U, s4 = i / U;
    int g = s4 / CPG, c = s4 % CPG;
    const float L2E = 1.4426950408889634f;
    unsigned ab[4]; __half wh[4];
    #pragma unroll
    for (int q = 0; q < 4; ++q) {
        size_t idx = (size_t)(s4 * 4 + q) * U + uo;
        float a = sg[idx] * L2E;
        __half2 h = __floats2half2_rn(a, mu[idx] * a);
        ab[q] = *reinterpret_cast<unsigned*>(&h);
        wh[q] = __float2half_rn(w[idx] * er[idx]);
    }
    __half2 w01 = __halves2half2(wh[0], wh[1]);
    __half2 w23 = __halves2half2(wh[2], wh[3]);
    int o = (c * U + uo) * 4 + g;
    ABI[o] = make_uint4(ab[0], ab[1], ab[2], ab[3]);
    WI[o]  = make_uint2(*reinterpret_cast<unsigned*>(&w01),
                        *reinterpret_cast<unsigned*>(&w23));
}

// linear fp16 pack (sens2k)
__global__ void prep_half(const float* __restrict__ sg, const float* __restrict__ mu,
                          const float* __restrict__ w, const float* __restrict__ er,
                          __half2* __restrict__ AB, __half* __restrict__ W, int n)
{
    int i = blockIdx.x * 256 + threadIdx.x;
    if (i >= n) return;
    const float L2E = 1.4426950408889634f;
    float a = sg[i] * L2E;
    AB[i] = __floats2half2_rn(a, mu[i] * a);
    W[i]  = __float2half_rn(w[i] * er[i]);
}

__global__ void prep_vec(const float* __restrict__ gleak, const float* __restrict__ vleak,
                         const float* __restrict__ cm,
                         float* __restrict__ cmt, float* __restrict__ nb,
                         float* __restrict__ db, int n)
{
    int i = blockIdx.x * 256 + threadIdx.x;
    if (i >= n) return;
    float c6 = cm[i] * 6.f;
    float gl = gleak[i];
    cmt[i] = c6;
    nb[i]  = gl * vleak[i];
    db[i]  = c6 + gl + 1e-8f;
}

// ---------------------------------------------------------------------------
// Layer 1: unchanged round-7 structure (2.3 ms, not the bottleneck).
// ---------------------------------------------------------------------------
__global__ __launch_bounds__(1024, 1) void ltc1(
    const float* __restrict__ x,
    const float* __restrict__ in_w, const float* __restrict__ in_b,
    const uint4* __restrict__ AB4s, const uint2* __restrict__ W2s,
    const uint4* __restrict__ AB4r, const uint2* __restrict__ W2r,
    const float* __restrict__ cmt, const float* __restrict__ nbv, const float* __restrict__ dbv,
    const float* __restrict__ ow, const float* __restrict__ ob,
    float* __restrict__ h1)
{
    const int b   = blockIdx.x;
    const int tid = threadIdx.x;
    const int uo  = tid & (U1 - 1);
    const int g   = tid >> 7;

    __shared__ float  v1[U1], ibuf[S1], nbs[U1], dbs[U1];
    __shared__ float2 red[8][U1];
    __shared__ uint4  AB4l[32 * U1];
    __shared__ uint2  W2l[32 * U1];

    for (int idx = tid; idx < 32 * U1; idx += 1024) {
        AB4l[idx] = AB4r[idx];
        W2l[idx]  = W2r[idx];
    }

    float c_cmt = 0, c_nb = 0, c_db = 0, c_iw = 0, c_ib = 0, c_ow = 0, c_ob = 0;
    if (tid < U1) {
        v1[tid] = 0.f;
        c_cmt = cmt[tid]; c_nb = nbv[tid]; c_db = dbv[tid];
        c_iw = in_w[tid]; c_ib = in_b[tid];
        c_ow = ow[tid];   c_ob = ob[tid];
    }
    const float* xb = x  + (size_t)b * T_STEPS * S1;
    float*       hb = h1 + (size_t)b * T_STEPS * U1;
    __syncthreads();

    for (int t = 0; t < T_STEPS; ++t) {
        if (tid < S1) ibuf[tid] = fmaf(xb[t * S1 + tid], c_iw, c_ib);
        __syncthreads();

        {
            float an = 0.f, ad = 0.f;
            #pragma unroll 2
            for (int c = 0; c < 4; ++c) {
                uint4 ab = AB4s[(g * 4 + c) * U1 + uo];
                uint2 w2 = W2s[(g * 4 + c) * U1 + uo];
                float4 vv = *reinterpret_cast<const float4*>(&ibuf[g * 16 + c * 4]);
                eval4(ab, w2, vv, an, ad);
            }
            red[g][uo] = make_float2(an, ad);
        }
        __syncthreads();
        if (tid < U1) {
            float sn = c_nb, sd = c_db;
            #pragma unroll
            for (int gg = 0; gg < 8; ++gg) { float2 r = red[gg][tid]; sn += r.x; sd += r.y; }
            nbs[tid] = sn; dbs[tid] = sd;
        }
        __syncthreads();

        for (int k = 0; k < NUNF; ++k) {
            float an = 0.f, ad = 0.f;
            #pragma unroll
            for (int c = 0; c < 4; ++c) {
                uint4 ab = AB4l[(g * 4 + c) * U1 + uo];
                uint2 w2 = W2l[(g * 4 + c) * U1 + uo];
                float4 vv = *reinterpret_cast<const float4*>(&v1[g * 16 + c * 4]);
                eval4(ab, w2, vv, an, ad);
            }
            red[g][uo] = make_float2(an, ad);
            __syncthreads();
            if (tid < U1) {
                float sn = nbs[tid], sd = dbs[tid];
                #pragma unroll
                for (int gg = 0; gg < 8; ++gg) { float2 r = red[gg][tid]; sn += r.x; sd += r.y; }
                v1[tid] = fmaf(c_cmt, v1[tid], sn) * fast_rcp(sd);
            }
            __syncthreads();
        }
        if (tid < U1) hb[t * U1 + tid] = fmaf(v1[tid], c_ow, c_ob);
    }
}

// ---------------------------------------------------------------------------
// Layer-2 sensory sums, fully parallel over (b,t).
// ---------------------------------------------------------------------------
__global__ __launch_bounds__(256, 4) void sens2k(
    const float* __restrict__ h1,
    const float* __restrict__ in_w, const float* __restrict__ in_b,
    const __half2* __restrict__ ABs, const __half* __restrict__ Ws,
    float* __restrict__ sn, float* __restrict__ sd)
{
    const int tid = threadIdx.x;
    const int b   = blockIdx.x >> 7;
    const int t0  = (blockIdx.x & 127) << 2;

    __shared__ float ibu[4][S2];
    for (int idx = tid; idx < 4 * S2; idx += 256) {
        int tt = idx >> 7, s = idx & (S2 - 1);
        ibu[tt][s] = fmaf(h1[((size_t)b * T_STEPS + t0 + tt) * S2 + s], in_w[s], in_b[s]);
    }
    __syncthreads();

    const int u = tid;
    float an0 = 0, an1 = 0, an2 = 0, an3 = 0;
    float ad0 = 0, ad1 = 0, ad2 = 0, ad3 = 0;
    for (int s = 0; s < S2; ++s) {
        __half2 ab = ABs[(size_t)s * U2 + u];
        float a  = __low2float(ab);
        float bb = __high2float(ab);
        float ww = __half2float(Ws[(size_t)s * U2 + u]);
        float aw = fabsf(ww);
        float r0 = fast_rcp(1.f + fast_exp2(fmaf(-a, ibu[0][s], bb)));
        float r1 = fast_rcp(1.f + fast_exp2(fmaf(-a, ibu[1][s], bb)));
        float r2 = fast_rcp(1.f + fast_exp2(fmaf(-a, ibu[2][s], bb)));
        float r3 = fast_rcp(1.f + fast_exp2(fmaf(-a, ibu[3][s], bb)));
        an0 = fmaf(ww, r0, an0); ad0 = fmaf(aw, r0, ad0);
        an1 = fmaf(ww, r1, an1); ad1 = fmaf(aw, r1, ad1);
        an2 = fmaf(ww, r2, an2); ad2 = fmaf(aw, r2, ad2);
        an3 = fmaf(ww, r3, an3); ad3 = fmaf(aw, r3, ad3);
    }
    size_t base = ((size_t)b * T_STEPS + t0) * U2 + u;
    sn[base]          = an0; sd[base]          = ad0;
    sn[base + U2]     = an1; sd[base + U2]     = ad1;
    sn[base + 2 * U2] = an2; sd[base + 2 * U2] = ad2;
    sn[base + 3 * U2] = an3; sd[base + 3 * U2] = ad3;
}

// ---------------------------------------------------------------------------
// Layer 2, butterfly layout: 1024 thr = 16 waves.
// lane = ul*4+g: g = row-group (0..3, 64 rows), u = w*16+ul = column.
// Per unfold: eval 16 chunks -> 2x shfl_xor butterfly -> v update in-register
// -> publish to double-buffered 4-copy vbuf -> ONE barrier.
// ---------------------------------------------------------------------------
template <bool HOIST>
__global__ __launch_bounds__(1024, 1) void ltc2(
    const float* __restrict__ h1,
    const float* __restrict__ in_w, const float* __restrict__ in_b,
    const uint4* __restrict__ ABsI, const uint2* __restrict__ WsI,
    const uint4* __restrict__ ABrI, const uint2* __restrict__ WrI,
    const float* __restrict__ sn, const float* __restrict__ sd,
    const float* __restrict__ cmt, const float* __restrict__ nbv, const float* __restrict__ dbv,
    const float* __restrict__ ow, const float* __restrict__ ob,
    float* __restrict__ h2)
{
    const int b    = blockIdx.x;
    const int tid  = threadIdx.x;
    const int w    = tid >> 6;
    const int lane = tid & 63;
    const int g    = lane & 3;
    const int ul   = lane >> 2;
    const int u    = w * 16 + ul;

    __shared__ uint4 ABl[RC2 * U2 * 4];     // 98304 B
    __shared__ uint2 Wl[RC2 * U2 * 4];      // 49152 B
    __shared__ float vbuf[2][4][68];        // dbuf x 4 bank-offset copies x 64 rows
    __shared__ float ibuf[S2];              // fallback sensory staging

    for (int idx = tid; idx < RC2 * U2 * 4; idx += 1024) {
        ABl[idx] = ABrI[idx];
        Wl[idx]  = WrI[idx];
    }
    for (int idx = tid; idx < 2 * 4 * 68; idx += 1024)
        (&vbuf[0][0][0])[idx] = 0.f;

    float v_reg = 0.f;
    const float c_cmt = cmt[u], c_nb = nbv[u], c_db = dbv[u];
    float c_ow = 0.f, c_ob = 0.f;
    if (u < 64) { c_ow = ow[u]; c_ob = ob[u]; }
    float c_iw = 0.f, c_ib = 0.f;
    if (!HOIST && tid < S2) { c_iw = in_w[tid]; c_ib = in_b[tid]; }

    const float* hb = h1 + (size_t)b * T_STEPS * S2;
    float*       op = h2 + (size_t)b * T_STEPS * 64;

    const uint4* pABr = ABrI + u * 4 + g;   // + c*1024 per chunk
    const uint2* pWr  = WrI  + u * 4 + g;
    const uint4* pABs = ABsI + u * 4 + g;
    const uint2* pWs  = WsI  + u * 4 + g;

    __syncthreads();
    int buf = 0;

    for (int t = 0; t < T_STEPS; ++t) {
        float nb_t, db_t;
        if (HOIST) {
            size_t ro = ((size_t)b * T_STEPS + t) * U2 + u;
            nb_t = c_nb + sn[ro];
            db_t = c_db + sd[ro];
        } else {
            if (tid < S2) ibuf[tid] = fmaf(hb[(size_t)t * S2 + tid], c_iw, c_ib);
            __syncthreads();
            float an = 0.f, ad = 0.f;
            #pragma unroll 2
            for (int c = 0; c < 8; ++c) {
                uint4 ab = pABs[c * 1024];
                uint2 w2 = pWs[c * 1024];
                float4 vv = *reinterpret_cast<const float4*>(&ibuf[g * 32 + c * 4]);
                eval4d(ab, w2, vv, an, ad);
            }
            an += __shfl_xor(an, 1, 64); ad += __shfl_xor(ad, 1, 64);
            an += __shfl_xor(an, 2, 64); ad += __shfl_xor(ad, 2, 64);
            nb_t = c_nb + an; db_t = c_db + ad;
        }

        #pragma unroll 1
        for (int k = 0; k < NUNF; ++k) {
            float an = 0.f, ad = 0.f;
            const float* vb = &vbuf[buf][g][0];
            // resident chunks (index = c*1024 + tid)
            #pragma unroll
            for (int c = 0; c < RC2; ++c) {
                uint4 ab = ABl[c * 1024 + tid];
                uint2 w2 = Wl[c * 1024 + tid];
                float4 vv = *reinterpret_cast<const float4*>(&vb[c * 4]);
                eval4d(ab, w2, vv, an, ad);
            }
            // streamed chunks
            #pragma unroll 2
            for (int c = RC2; c < 16; ++c) {
                uint4 ab = pABr[c * 1024];
                uint2 w2 = pWr[c * 1024];
                float4 vv = *reinterpret_cast<const float4*>(&vb[c * 4]);
                eval4d(ab, w2, vv, an, ad);
            }
            an += __shfl_xor(an, 1, 64); ad += __shfl_xor(ad, 1, 64);
            an += __shfl_xor(an, 2, 64); ad += __shfl_xor(ad, 2, 64);
            float wn = nb_t + an;
            float wd = db_t + ad;
            v_reg = fmaf(c_cmt, v_reg, wn) * fast_rcp(wd);
            if (g == 0) vbuf[buf ^ 1][w >> 2][(w & 3) * 16 + ul] = v_reg;
            buf ^= 1;
            __syncthreads();
        }
        if (u < 64 && g == 0) op[(size_t)t * 64 + u] = fmaf(v_reg, c_ow, c_ob);
    }
}

// ---------------------------------------------------------------------------
// FC head: out[b,t,o] = fcb[o] + sum_k h2[b,t,k] * fcw[o,k]
// ---------------------------------------------------------------------------
__global__ __launch_bounds__(512, 1) void fc_head(
    const float* __restrict__ h2, const float* __restrict__ fcw,
    const float* __restrict__ fcb, float* __restrict__ out)
{
    __shared__ float fwT[64 * 64];
    __shared__ float hs[8 * 64];
    const int tid = threadIdx.x;
    for (int i = tid; i < 64 * 64; i += 512) {
        int o = i >> 6, k = i & 63;
        fwT[k * 64 + o] = fcw[i];
    }
    size_t base = (size_t)blockIdx.x * 8 * 64;
    hs[tid] = h2[base + tid];
    __syncthreads();
    const int o = tid & 63, tt = tid >> 6;
    float acc = fcb[o];
    #pragma unroll
    for (int k = 0; k < 64; ++k)
        acc = fmaf(hs[tt * 64 + k], fwT[k * 64 + o], acc);
    out[base + tt * 64 + o] = acc;
}

// ---------------------------------------------------------------------------
extern "C" void kernel_launch(void* const* d_in, const int* in_sizes, int n_in,
                              void* d_out, int out_size, void* d_ws, size_t ws_size,
                              hipStream_t stream)
{
    (void)in_sizes; (void)n_in; (void)out_size;

    const float* x      = (const float*)d_in[0];
    const float* l1_iw  = (const float*)d_in[1];
    const float* l1_ib  = (const float*)d_in[2];
    const float* l1_sw  = (const float*)d_in[3];
    const float* l1_ss  = (const float*)d_in[4];
    const float* l1_smu = (const float*)d_in[5];
    const float* l1_se  = (const float*)d_in[6];
    const float* l1_w   = (const float*)d_in[8];
    const float* l1_sg  = (const float*)d_in[9];
    const float* l1_mu  = (const float*)d_in[10];
    const float* l1_er  = (const float*)d_in[11];
    const float* l1_gl  = (const float*)d_in[13];
    const float* l1_vl  = (const float*)d_in[14];
    const float* l1_cm  = (const float*)d_in[15];
    const float* l1_ow  = (const float*)d_in[16];
    const float* l1_ob  = (const float*)d_in[17];
    const float* l2_iw  = (const float*)d_in[18];
    const float* l2_ib  = (const float*)d_in[19];
    const float* l2_sw  = (const float*)d_in[20];
    const float* l2_ss  = (const float*)d_in[21];
    const float* l2_smu = (const float*)d_in[22];
    const float* l2_se  = (const float*)d_in[23];
    const float* l2_w   = (const float*)d_in[25];
    const float* l2_sg  = (const float*)d_in[26];
    const float* l2_mu  = (const float*)d_in[27];
    const float* l2_er  = (const float*)d_in[28];
    const float* l2_gl  = (const float*)d_in[30];
    const float* l2_vl  = (const float*)d_in[31];
    const float* l2_cm  = (const float*)d_in[32];
    const float* l2_ow  = (const float*)d_in[33];
    const float* l2_ob  = (const float*)d_in[34];
    const float* fcw    = (const float*)d_in[35];
    const float* fcb    = (const float*)d_in[36];

    char*  base = (char*)d_ws;
    size_t off  = 0;
    auto alloc = [&](size_t bytes) -> char* {
        char* p = base + off;
        off += (bytes + 255) & ~(size_t)255;
        return p;
    };

    float* h1 = (float*)alloc((size_t)B_SZ * T_STEPS * U1 * 4);
    float* h2 = (float*)alloc((size_t)B_SZ * T_STEPS * 64 * 4);
    // ltc1 linear-chunked params
    uint4* AB4s1 = (uint4*)alloc((size_t)(S1 / 4) * U1 * 16);
    uint2* W2s1  = (uint2*)alloc((size_t)(S1 / 4) * U1 * 8);
    uint4* AB4r1 = (uint4*)alloc((size_t)(U1 / 4) * U1 * 16);
    uint2* W2r1  = (uint2*)alloc((size_t)(U1 / 4) * U1 * 8);
    // ltc2 interleaved params
    uint4* ABsI2 = (uint4*)alloc((size_t)(S2 / 4) * U2 * 16);
    uint2* WsI2  = (uint2*)alloc((size_t)(S2 / 4) * U2 * 8);
    uint4* ABrI2 = (uint4*)alloc((size_t)(U2 / 4) * U2 * 16);
    uint2* WrI2  = (uint2*)alloc((size_t)(U2 / 4) * U2 * 8);
    // linear fp16 (sens2k)
    __half2* AB2s = (__half2*)alloc((size_t)S2 * U2 * 4);
    __half*  W2s  = (__half*) alloc((size_t)S2 * U2 * 2);
    float* cmt1 = (float*)alloc(U1 * 4);
    float* nb1  = (float*)alloc(U1 * 4);
    float* db1  = (float*)alloc(U1 * 4);
    float* cmt2 = (float*)alloc(U2 * 4);
    float* nb2  = (float*)alloc(U2 * 4);
    float* db2  = (float*)alloc(U2 * 4);

    size_t sens_bytes = (size_t)B_SZ * T_STEPS * U2 * 4;
    bool hoist = (off + 2 * sens_bytes + 512) <= ws_size;
    float* sn2 = nullptr; float* sd2 = nullptr;
    if (hoist) {
        sn2 = (float*)alloc(sens_bytes);
        sd2 = (float*)alloc(sens_bytes);
    }

    prep_chunk<<<((S1/4)*U1 + 255)/256, 256, 0, stream>>>(l1_ss, l1_smu, l1_sw, l1_se, AB4s1, W2s1, S1/4, U1);
    prep_chunk<<<((U1/4)*U1 + 255)/256, 256, 0, stream>>>(l1_sg, l1_mu,  l1_w,  l1_er, AB4r1, W2r1, U1/4, U1);
    prep_ilv<<<((S2/4)*U2 + 255)/256, 256, 0, stream>>>(l2_ss, l2_smu, l2_sw, l2_se, ABsI2, WsI2, S2/4, U2, 8);
    prep_ilv<<<((U2/4)*U2 + 255)/256, 256, 0, stream>>>(l2_sg, l2_mu,  l2_w,  l2_er, ABrI2, WrI2, U2/4, U2, 16);
    prep_half<<<(S2 * U2 + 255)/256, 256, 0, stream>>>(l2_ss, l2_smu, l2_sw, l2_se, AB2s, W2s, S2 * U2);
    prep_vec<<<1, 256, 0, stream>>>(l1_gl, l1_vl, l1_cm, cmt1, nb1, db1, U1);
    prep_vec<<<1, 256, 0, stream>>>(l2_gl, l2_vl, l2_cm, cmt2, nb2, db2, U2);

    ltc1<<<B_SZ, 1024, 0, stream>>>(x, l1_iw, l1_ib, AB4s1, W2s1, AB4r1, W2r1,
                                    cmt1, nb1, db1, l1_ow, l1_ob, h1);

    if (hoist) {
        sens2k<<<B_SZ * (T_STEPS / 4), 256, 0, stream>>>(h1, l2_iw, l2_ib, AB2s, W2s, sn2, sd2);
        ltc2<true><<<B_SZ, 1024, 0, stream>>>(h1, l2_iw, l2_ib, ABsI2, WsI2, ABrI2, WrI2,
                                              sn2, sd2, cmt2, nb2, db2, l2_ow, l2_ob, h2);
    } else {
        ltc2<false><<<B_SZ, 1024, 0, stream>>>(h1, l2_iw, l2_ib, ABsI2, WsI2, ABrI2, WrI2,
                                               nullptr, nullptr, cmt2, nb2, db2, l2_ow, l2_ob, h2);
    }
    fc_head<<<B_SZ * T_STEPS / 8, 512, 0, stream>>>(h2, fcw, fcb, (float*)d_out);
}